// Round 10
// baseline (1629.424 us; speedup 1.0000x reference)
//
#include <hip/hip_runtime.h>
#include <math.h>

#define GN 8192
#define GF 64
#define GFIN 256
#define NEG 0.2f
#define NFINE 256
#define FCH 32      // ranks per fine chunk

// ===== MEASUREMENT ROUND: internal repetition to force each kernel past the
// ~157us poison-fill cutoff in rocprof top-5. Final state identical to R9.
#define WH_REP   48
#define RANK_REP 32
#define SCAN_REP 128
#define OUT_REP  64

// workspace layout (floats)
#define OFF_WH   0
#define OFF_S1   (GN*GF)
#define OFF_S2   (OFF_S1 + GN)
#define OFF_ZS   (OFF_S2 + GN)
#define OFF_IDX  (OFF_ZS + GN)              // int32: rank -> original row
#define OFF_FA   (OFF_IDX + GN)             // NFINE*GF fine sums, A (atomic)
#define OFF_FB   (OFF_FA + NFINE*GF)        // NFINE*GF fine sums, B (atomic)
#define OFF_FSA  (OFF_FB + NFINE*GF)        // NFINE scalar sums, A
#define OFF_FSB  (OFF_FSA + NFINE)          // NFINE scalar sums, B
#define OFF_OFA  (OFF_FSB + NFINE)          // NFINE*GF exclusive suffix, A
#define OFF_OFB  (OFF_OFA + NFINE*GF)       // NFINE*GF exclusive prefix, B
#define OFF_OSA  (OFF_OFB + NFINE*GF)       // NFINE scalar, A
#define OFF_OSB  (OFF_OSA + NFINE)          // NFINE scalar, B
#define ZERO_CNT (2*NFINE*GF + 2*NFINE)     // FA..FSB contiguous

// Kernel 1: Wh = h @ W, s1, s2; zero fine tables. Repeated WH_REP x.
__global__ __launch_bounds__(512) void k_wh(const float* __restrict__ h,
        const float* __restrict__ W, const float* __restrict__ a,
        float* __restrict__ wsf) {
    float* Wh = wsf + OFF_WH;
    float* s1 = wsf + OFF_S1;
    float* s2 = wsf + OFF_S2;
    __shared__ float WlT[GF*GFIN];           // 64 KB
    int t = threadIdx.x, b = blockIdx.x;
    int lane = t & 63;
    for (int rep = 0; rep < WH_REP; ++rep) {
        int zm = b*512 + t;
        if (zm < ZERO_CNT) wsf[OFF_FA + zm] = 0.f;
        const float4* W4 = (const float4*)W;
        #pragma unroll
        for (int m = 0; m < 8; ++m) {
            int g = t + m*512;
            float4 v = W4[g];
            int k = g >> 4;
            int c0 = (g & 15) * 4;
            WlT[(c0  )*GFIN + (k ^ (((c0  )&7)<<2))] = v.x;
            WlT[(c0+1)*GFIN + (k ^ (((c0+1)&7)<<2))] = v.y;
            WlT[(c0+2)*GFIN + (k ^ (((c0+2)&7)<<2))] = v.z;
            WlT[(c0+3)*GFIN + (k ^ (((c0+3)&7)<<2))] = v.w;
        }
        __syncthreads();
        int wid = __builtin_amdgcn_readfirstlane(t >> 6);
        int row0 = b*32 + wid*4;
        const float* hrow = h + (size_t)row0 * GFIN;
        float acc[4] = {0.f,0.f,0.f,0.f};
        const float4* WlT4 = (const float4*)WlT;
        int cbase = lane * (GFIN/4);
        int sw = lane & 7;
        #pragma unroll 8
        for (int k4 = 0; k4 < GFIN/4; ++k4) {
            float4 wv = WlT4[cbase + (k4 ^ sw)];
            int kk = k4*4;
            #pragma unroll
            for (int q = 0; q < 4; ++q) {
                acc[q] += hrow[q*GFIN + kk  ] * wv.x;
                acc[q] += hrow[q*GFIN + kk+1] * wv.y;
                acc[q] += hrow[q*GFIN + kk+2] * wv.z;
                acc[q] += hrow[q*GFIN + kk+3] * wv.w;
            }
        }
        float a1 = a[lane], a2 = a[GF + lane];
        #pragma unroll
        for (int q = 0; q < 4; ++q) {
            int row = row0 + q;
            Wh[(size_t)row*GF + lane] = acc[q];
            float v1 = acc[q]*a1, v2 = acc[q]*a2;
            #pragma unroll
            for (int o = 32; o > 0; o >>= 1) { v1 += __shfl_xor(v1, o); v2 += __shfl_xor(v2, o); }
            if (lane == 0) { s1[row] = v1; s2[row] = v2; }
        }
        __syncthreads();                     // protect WlT re-stage next rep
    }
}

// Kernel 2: rank-sort s2; sweep repeated RANK_REP x; atomic scatter ONCE after
// the loop (idempotence: tables zeroed by k_wh, scattered exactly once).
__global__ __launch_bounds__(512) void k_rank(const float* __restrict__ Whg,
        float* __restrict__ wsf) {
    __shared__ float zl[GN];                 // 32 KB s2 copy
    __shared__ int rl[32];
    __shared__ float redm[8];
    const float* s2 = wsf + OFF_S2;
    float* zs = wsf + OFF_ZS;
    int* idx = (int*)(wsf + OFF_IDX);
    float* fineA = wsf + OFF_FA;
    float* fineB = wsf + OFF_FB;
    float* fSA = wsf + OFF_FSA;
    float* fSB = wsf + OFF_FSB;
    int t = threadIdx.x, b = blockIdx.x;
    int lane = t & 63, wid = t >> 6;
    float Z = 0.f;
    for (int rep = 0; rep < RANK_REP; ++rep) {
        const float4* s4 = (const float4*)s2;
        float4* z4 = (float4*)zl;
        float mx = -1e30f;
        for (int m = t; m < GN/4; m += 512) {
            float4 v = s4[m]; z4[m] = v;
            mx = fmaxf(fmaxf(mx, v.x), fmaxf(fmaxf(v.y, v.z), v.w));
        }
        #pragma unroll
        for (int o = 32; o > 0; o >>= 1) mx = fmaxf(mx, __shfl_xor(mx, o));
        if (lane == 0) redm[wid] = mx;
        __syncthreads();
        Z = redm[0];
        #pragma unroll
        for (int w2 = 1; w2 < 8; ++w2) Z = fmaxf(Z, redm[w2]);
        int jl = t >> 4, sl = t & 15;
        int j = b*32 + jl;
        float zj = zl[j];
        int cnt = 0;
        #pragma unroll 4
        for (int i = 0; i < GN/64; ++i) {
            int m4 = i*16 + sl;
            float4 v = ((const float4*)zl)[m4];
            int mb = m4*4;
            cnt += (v.x < zj) || (v.x == zj && mb   < j);
            cnt += (v.y < zj) || (v.y == zj && mb+1 < j);
            cnt += (v.z < zj) || (v.z == zj && mb+2 < j);
            cnt += (v.w < zj) || (v.w == zj && mb+3 < j);
        }
        cnt += __shfl_xor(cnt, 1);
        cnt += __shfl_xor(cnt, 2);
        cnt += __shfl_xor(cnt, 4);
        cnt += __shfl_xor(cnt, 8);
        if (sl == 0) { zs[cnt] = zj; idx[cnt] = j; rl[jl] = cnt; }
        __syncthreads();                     // rl/zl stable for next rep/scatter
    }
    // atomic scatter: 8 waves x 4 j's = the block's 32 rows (coalesced Wh)
    #pragma unroll
    for (int q = 0; q < 4; ++q) {
        int jj = wid*4 + q;
        int jg = b*32 + jj;
        int r = rl[jj];
        float d = zl[jg] - Z;
        float tA = __expf(d);
        float tB = __expf(NEG*d);
        float w = Whg[(size_t)jg*GF + lane];
        int fc = r >> 5;                     // FCH = 32
        atomicAdd(&fineA[fc*GF + lane], tA*w);
        atomicAdd(&fineB[fc*GF + lane], tB*w);
        if (lane == 0) atomicAdd(&fSA[fc], tA);
        if (lane == 1) atomicAdd(&fSB[fc], tB);
    }
}

// Kernel 3: pure scan over 256 fine-chunk totals. Repeated SCAN_REP x.
// NOTE: no __restrict__ (blocks cross-rep load hoisting via aliasing).
__global__ __launch_bounds__(256) void k_scan(float* wsf) {
    __shared__ float stg[NFINE];
    __shared__ float wred[4];
    const float* fineA = wsf + OFF_FA;
    const float* fineB = wsf + OFF_FB;
    const float* fSA = wsf + OFF_FSA;
    const float* fSB = wsf + OFF_FSB;
    float* ofA = wsf + OFF_OFA;
    float* ofB = wsf + OFF_OFB;
    float* osA = wsf + OFF_OSA;
    float* osB = wsf + OFF_OSB;
    int c = blockIdx.x;
    int t = threadIdx.x, lane = t & 63, wid = t >> 6;
    for (int rep = 0; rep < SCAN_REP; ++rep) {
        float fA = (c < 64) ? fineA[t*GF + c] : fSA[t];
        float fB = (c < 64) ? fineB[t*GF + c] : fSB[t];
        {
            float ws = fB;
            #pragma unroll
            for (int o = 1; o < 64; o <<= 1) { float y = __shfl_up(ws, o); if (lane >= o) ws += y; }
            if (lane == 63) wred[wid] = ws;
            __syncthreads();
            float blkoff = 0.f;
            #pragma unroll
            for (int w2 = 0; w2 < 4; ++w2) { float x = wred[w2]; if (w2 < wid) blkoff += x; }
            float exB = blkoff + ws - fB;
            if (c < 64) ofB[t*GF + c] = exB; else osB[t] = exB;
        }
        __syncthreads();
        stg[t] = fA;
        __syncthreads();
        {
            int rt = NFINE-1-t;
            float vA = stg[rt];
            float ws = vA;
            #pragma unroll
            for (int o = 1; o < 64; o <<= 1) { float y = __shfl_up(ws, o); if (lane >= o) ws += y; }
            __syncthreads();
            if (lane == 63) wred[wid] = ws;
            __syncthreads();
            float blkoff = 0.f;
            #pragma unroll
            for (int w2 = 0; w2 < 4; ++w2) { float x = wred[w2]; if (w2 < wid) blkoff += x; }
            float exA = blkoff + ws - vA;
            if (c < 64) ofA[rt*GF + c] = exA; else osA[rt] = exA;
        }
        __syncthreads();                     // wred/stg stable for next rep
    }
}

// Kernel 4: per-row output. Repeated OUT_REP x. No __restrict__ (see k_scan).
__global__ __launch_bounds__(256) void k_out(const float* wsf, float* out) {
    const float* Wh = wsf + OFF_WH;
    const float* s1 = wsf + OFF_S1;
    const float* zs = wsf + OFF_ZS;
    const int* idx = (const int*)(wsf + OFF_IDX);
    const float* ofA = wsf + OFF_OFA;
    const float* ofB = wsf + OFF_OFB;
    const float* osA = wsf + OFF_OSA;
    const float* osB = wsf + OFF_OSB;
    int t = threadIdx.x;
    int wid = t >> 6, lane = t & 63;
    int i = blockIdx.x*4 + wid;
    for (int rep = 0; rep < OUT_REP; ++rep) {
        float s1i = s1[i];
        float Z = zs[GN-1];
        float g = s1i + Z;
        float m = (g >= 0.f) ? g : NEG*g;    // LeakyReLU(g) = row max of e
        float aA = __expf(g - m);            // <= 1
        float aB = __expf(NEG*g - m);        // <= 1
        float tgt = -s1i;
        int lo = 0, hi = GN;                 // lower_bound: first zs[k] >= tgt
        #pragma unroll
        for (int it = 0; it < 13; ++it) {
            int mid = (lo + hi) >> 1;
            if (zs[mid] < tgt) lo = mid + 1; else hi = mid;
        }
        int k = lo;
        int fc = __builtin_amdgcn_readfirstlane(min(k >> 5, NFINE-1));
        float va = ofA[fc*GF + lane];        // sum over chunks > fc (A side)
        float vb = ofB[fc*GF + lane];        // sum over chunks < fc (B side)
        float sa = osA[fc], pb = osB[fc];
        #pragma unroll 8
        for (int q = 0; q < FCH; ++q) {
            int r = fc*FCH + q;
            float zr = zs[r];
            int ir = idx[r];
            float w = Wh[(size_t)ir*GF + lane];
            float d = zr - Z;
            if (r >= k) { float tA = __expf(d);     va += tA*w; sa += tA; }
            else        { float tB = __expf(NEG*d); vb += tB*w; pb += tB; }
        }
        out[(size_t)i*GF + lane] = (aA*va + aB*vb) / (aA*sa + aB*pb);
    }
}

extern "C" void kernel_launch(void* const* d_in, const int* in_sizes, int n_in,
                              void* d_out, int out_size, void* d_ws, size_t ws_size,
                              hipStream_t stream) {
    const float* h = (const float*)d_in[0];
    // d_in[1] = adj (unused by the reference forward)
    const float* W = (const float*)d_in[2];
    const float* a = (const float*)d_in[3];
    float* wsf = (float*)d_ws;
    float* out = (float*)d_out;

    hipLaunchKernelGGL(k_wh,   dim3(GN/32), dim3(512), 0, stream, h, W, a, wsf);
    hipLaunchKernelGGL(k_rank, dim3(GN/32), dim3(512), 0, stream, wsf + OFF_WH, wsf);
    hipLaunchKernelGGL(k_scan, dim3(65),    dim3(256), 0, stream, wsf);
    hipLaunchKernelGGL(k_out,  dim3(GN/4),  dim3(256), 0, stream, wsf, out);
}

// Round 11
// 102.405 us; speedup vs baseline: 15.9115x; 15.9115x over previous
//
#include <hip/hip_runtime.h>
#include <math.h>

#define GN 8192
#define GF 64
#define GFIN 256
#define NEG 0.2f
#define NFINE 512
#define FCH 16      // ranks per fine chunk
#define NSEG 64     // 8 buckets per segment

// workspace layout (floats)
#define OFF_WH   0
#define OFF_S1   (GN*GF)
#define OFF_S2   (OFF_S1 + GN)
#define OFF_ZS   (OFF_S2 + GN)
#define OFF_IDX  (OFF_ZS + GN)              // int32: rank -> original row
#define OFF_FA   (OFF_IDX + GN)             // NFINE*GF fine sums, A (atomic)
#define OFF_FB   (OFF_FA + NFINE*GF)        // NFINE*GF fine sums, B (atomic)
#define OFF_FSA  (OFF_FB + NFINE*GF)        // NFINE scalar sums, A
#define OFF_FSB  (OFF_FSA + NFINE)          // NFINE scalar sums, B
#define ZERO_CNT (2*NFINE*GF + 2*NFINE)     // 66560 = 256 blocks * 260

// Kernel 1: Wh = h @ W, s1 = Wh@a1, s2 = Wh@a2; zero atomic tables.
// R3-proven pattern: W row-major in LDS, b32 broadcast reads (2-way = free),
// h via wave-uniform s_loads, 8 rows/wave.
__global__ __launch_bounds__(256) void k_wh(const float* __restrict__ h,
        const float* __restrict__ W, const float* __restrict__ a,
        float* __restrict__ wsf) {
    float* Wh = wsf + OFF_WH;
    float* s1 = wsf + OFF_S1;
    float* s2 = wsf + OFF_S2;
    __shared__ float Wl[GFIN*GF];            // 64 KB
    int t = threadIdx.x, b = blockIdx.x;
    int lane = t & 63;
    for (int u = t; u < 260; u += 256) wsf[OFF_FA + b*260 + u] = 0.f;
    const float4* W4 = (const float4*)W;
    float4* Wl4 = (float4*)Wl;
    #pragma unroll
    for (int m = 0; m < 16; ++m) Wl4[t + m*256] = W4[t + m*256];
    __syncthreads();
    int wid = __builtin_amdgcn_readfirstlane(t >> 6);   // SGPR wave id
    int row0 = b*32 + wid*8;
    const float* hrow = h + (size_t)row0 * GFIN;        // wave-uniform base
    float acc[8] = {0.f,0.f,0.f,0.f,0.f,0.f,0.f,0.f};
    #pragma unroll 8
    for (int k = 0; k < GFIN; ++k) {
        float wv = Wl[k*GF + lane];
        #pragma unroll
        for (int q = 0; q < 8; ++q) acc[q] += hrow[q*GFIN + k] * wv;
    }
    float a1 = a[lane], a2 = a[GF + lane];
    #pragma unroll
    for (int q = 0; q < 8; ++q) {
        int row = row0 + q;
        Wh[(size_t)row*GF + lane] = acc[q];
        float v1 = acc[q]*a1, v2 = acc[q]*a2;
        #pragma unroll
        for (int o = 32; o > 0; o >>= 1) { v1 += __shfl_xor(v1, o); v2 += __shfl_xor(v2, o); }
        if (lane == 0) { s1[row] = v1; s2[row] = v2; }
    }
}

// Kernel 2: rank-sort s2 (strict total order, index tiebreak) + atomic scatter
// of exp-weighted Wh rows into fine-chunk tables (rank>>4). R9-proven.
__global__ __launch_bounds__(512) void k_rank(const float* __restrict__ Whg,
        float* __restrict__ wsf) {
    __shared__ float zl[GN];                 // 32 KB s2 copy
    __shared__ int rl[32];
    __shared__ float redm[8];
    const float* s2 = wsf + OFF_S2;
    float* zs = wsf + OFF_ZS;
    int* idx = (int*)(wsf + OFF_IDX);
    float* fineA = wsf + OFF_FA;
    float* fineB = wsf + OFF_FB;
    float* fSA = wsf + OFF_FSA;
    float* fSB = wsf + OFF_FSB;
    int t = threadIdx.x, b = blockIdx.x;
    int lane = t & 63, wid = t >> 6;
    const float4* s4 = (const float4*)s2;
    float4* z4 = (float4*)zl;
    float mx = -1e30f;
    for (int m = t; m < GN/4; m += 512) {
        float4 v = s4[m]; z4[m] = v;
        mx = fmaxf(fmaxf(mx, v.x), fmaxf(fmaxf(v.y, v.z), v.w));
    }
    #pragma unroll
    for (int o = 32; o > 0; o >>= 1) mx = fmaxf(mx, __shfl_xor(mx, o));
    if (lane == 0) redm[wid] = mx;
    __syncthreads();
    float Z = redm[0];
    #pragma unroll
    for (int w2 = 1; w2 < 8; ++w2) Z = fmaxf(Z, redm[w2]);
    // rank: 32 j's per block, 16 slices each
    int jl = t >> 4, sl = t & 15;
    int j = b*32 + jl;
    float zj = zl[j];
    int cnt = 0;
    #pragma unroll 4
    for (int i = 0; i < GN/64; ++i) {        // 128 iters x float4
        int m4 = i*16 + sl;
        float4 v = z4[m4];
        int mb = m4*4;
        cnt += (v.x < zj) || (v.x == zj && mb   < j);
        cnt += (v.y < zj) || (v.y == zj && mb+1 < j);
        cnt += (v.z < zj) || (v.z == zj && mb+2 < j);
        cnt += (v.w < zj) || (v.w == zj && mb+3 < j);
    }
    cnt += __shfl_xor(cnt, 1);
    cnt += __shfl_xor(cnt, 2);
    cnt += __shfl_xor(cnt, 4);
    cnt += __shfl_xor(cnt, 8);
    if (sl == 0) { zs[cnt] = zj; idx[cnt] = j; rl[jl] = cnt; }
    __syncthreads();
    // atomic scatter: 8 waves x 4 j's = the block's 32 rows (coalesced Wh)
    #pragma unroll
    for (int q = 0; q < 4; ++q) {
        int jj = wid*4 + q;
        int jg = b*32 + jj;
        int r = rl[jj];
        float d = zl[jg] - Z;
        float tA = __expf(d);
        float tB = __expf(NEG*d);
        float w = Whg[(size_t)jg*GF + lane];
        int fc = r >> 4;                     // FCH = 16
        atomicAdd(&fineA[fc*GF + lane], tA*w);
        atomicAdd(&fineB[fc*GF + lane], tB*w);
        if (lane == 0) atomicAdd(&fSA[fc], tA);
        if (lane == 1) atomicAdd(&fSB[fc], tB);
    }
}

// Kernel 3: outputs WITH embedded scan (k_scan node deleted).
// 128 blocks x 512 thr (8 waves x 8 rows). Per block: 64-segment sums of the
// fine tables in LDS, in-place seg-level suffix(A)/prefix(B) scans, chunk-max
// keys for a 9-step LDS search; per row: 1 LDS read + <=7 in-seg global reads
// + exact 16-element value-tested boundary walk.
__global__ __launch_bounds__(512) void k_out(const float* __restrict__ wsf,
        float* __restrict__ out) {
    __shared__ float ckey[NFINE];            // 2 KB chunk-max keys
    __shared__ float segA[NSEG][GF];         // 16 KB -> scanned: suffix-excl
    __shared__ float segB[NSEG][GF];         // 16 KB -> scanned: prefix-excl
    __shared__ float sgA[NSEG];              // scalar seg sums -> suffix-excl
    __shared__ float sgB[NSEG];              // -> prefix-excl
    const float* Wh = wsf + OFF_WH;
    const float* s1 = wsf + OFF_S1;
    const float* zs = wsf + OFF_ZS;
    const int* idx = (const int*)(wsf + OFF_IDX);
    const float* fineA = wsf + OFF_FA;
    const float* fineB = wsf + OFF_FB;
    const float* fSA = wsf + OFF_FSA;
    const float* fSB = wsf + OFF_FSB;
    int t = threadIdx.x, b = blockIdx.x;
    int lane = t & 63, wid = t >> 6;
    if (t < NFINE) ckey[t] = zs[t*FCH + FCH-1];
    {   // raw segment sums: thread (c = t&63, g = t>>6) handles segs g+8u
        int c = t & 63, g = t >> 6;
        #pragma unroll
        for (int u = 0; u < 8; ++u) {
            int s = g*8 + u;
            float sa = 0.f, sb = 0.f;
            #pragma unroll
            for (int e = 0; e < 8; ++e) {
                int bb = s*8 + e;
                sa += fineA[bb*GF + c];
                sb += fineB[bb*GF + c];
            }
            segA[s][c] = sa; segB[s][c] = sb;
        }
    }
    if (t < NSEG) {                          // scalar seg sums
        float sa = 0.f, sb = 0.f;
        #pragma unroll
        for (int e = 0; e < 8; ++e) { sa += fSA[t*8+e]; sb += fSB[t*8+e]; }
        sgA[t] = sa; sgB[t] = sb;
    }
    __syncthreads();
    if (t < 64) {                            // in-place vector seg scans
        float accA = 0.f;
        for (int s = NSEG-1; s >= 0; --s) { float x = segA[s][t]; segA[s][t] = accA; accA += x; }
        float accB = 0.f;
        for (int s = 0; s < NSEG; ++s)    { float x = segB[s][t]; segB[s][t] = accB; accB += x; }
    } else if (t == 64) {                    // scalar seg scans (serial, tiny)
        float accA = 0.f;
        for (int s = NSEG-1; s >= 0; --s) { float x = sgA[s]; sgA[s] = accA; accA += x; }
        float accB = 0.f;
        for (int s = 0; s < NSEG; ++s)    { float x = sgB[s]; sgB[s] = accB; accB += x; }
    }
    __syncthreads();
    float Zv = zs[GN-1];
    int i0 = b*64 + wid*8;
    for (int rq = 0; rq < 8; ++rq) {
        int i = i0 + rq;
        float s1i = s1[i];
        float g = s1i + Zv;
        float m = (g >= 0.f) ? g : NEG*g;    // LeakyReLU(g) = row max of e
        float aA = __expf(g - m);            // <= 1
        float aB = __expf(NEG*g - m);        // <= 1
        float tau = -s1i;
        int lo = 0, hi = NFINE;              // first chunk with ckey >= tau
        #pragma unroll
        for (int it = 0; it < 9; ++it) {
            int mid = (lo + hi) >> 1;
            if (ckey[mid] < tau) lo = mid + 1; else hi = mid;
        }
        int fc = __builtin_amdgcn_readfirstlane(min(lo, NFINE-1));
        int s = fc >> 3;
        float va = segA[s][lane], vb = segB[s][lane];
        float sa = sgA[s],        pb = sgB[s];
        for (int bb = s*8; bb < fc; ++bb)       { vb += fineB[bb*GF + lane]; pb += fSB[bb]; }
        for (int bb = fc+1; bb < s*8+8; ++bb)   { va += fineA[bb*GF + lane]; sa += fSA[bb]; }
        #pragma unroll
        for (int e = 0; e < FCH; ++e) {      // exact boundary walk (value test)
            int r = fc*FCH + e;
            float zr = zs[r];
            int j = idx[r];
            float w = Wh[(size_t)j*GF + lane];
            float d = zr - Zv;
            if (zr >= tau) { float tA = __expf(d);     va += tA*w; sa += tA; }
            else           { float tB = __expf(NEG*d); vb += tB*w; pb += tB; }
        }
        out[(size_t)i*GF + lane] = (aA*va + aB*vb) / (aA*sa + aB*pb);
    }
}

extern "C" void kernel_launch(void* const* d_in, const int* in_sizes, int n_in,
                              void* d_out, int out_size, void* d_ws, size_t ws_size,
                              hipStream_t stream) {
    const float* h = (const float*)d_in[0];
    // d_in[1] = adj (unused by the reference forward)
    const float* W = (const float*)d_in[2];
    const float* a = (const float*)d_in[3];
    float* wsf = (float*)d_ws;
    float* out = (float*)d_out;

    hipLaunchKernelGGL(k_wh,   dim3(GN/32), dim3(256), 0, stream, h, W, a, wsf);
    hipLaunchKernelGGL(k_rank, dim3(GN/32), dim3(512), 0, stream, wsf + OFF_WH, wsf);
    hipLaunchKernelGGL(k_out,  dim3(GN/64), dim3(512), 0, stream, wsf, out);
}